// Round 10
// baseline (151.448 us; speedup 1.0000x reference)
//
#include <hip/hip_runtime.h>

#define N_NODES 100000
#define N_EDGES 3200000
#define F_IN 128
#define F_HID 16

#define BK_LG 9
#define BK_NODES 512                                  // nodes per bucket
#define NBK ((N_NODES + BK_NODES - 1) / BK_NODES)     // 196 buckets
#define NBK_P 256                                     // padded scan width
#define BCAP 17664                                    // avg 16327, +10 sigma
#define CH1 2048                                      // edges per bin chunk
#define NCH1 ((N_EDGES + CH1 - 1) / CH1)              // 1563
#define CUR_STRIDE 16                                 // striped cursors

__device__ __forceinline__ unsigned short f2bf_rne(float f) {
    unsigned u = __float_as_uint(f);
    u += 0x7FFFu + ((u >> 16) & 1u);
    return (unsigned short)(u >> 16);
}

// ---------------------------------------------------------------------------
// K1 (fused producer, 24.8KB LDS union -> 6 blocks/CU):
//   even blocks: xw0 tile (64 rows, x staged as bf16) -> z0b
//   odd  blocks: bin chunk (2048 edges) into 196 x 512-node buckets
// Packed edge: .x = w bits, .y = src | (dst_local9 << 17).
// ---------------------------------------------------------------------------
__global__ __launch_bounds__(256) void k_pre(const float* __restrict__ x,
                                             const float* __restrict__ W0,
                                             unsigned short* __restrict__ z0b,
                                             const int* __restrict__ src,
                                             const int* __restrict__ dst,
                                             const float* __restrict__ ew,
                                             int* __restrict__ cursorC,
                                             int2* __restrict__ ebinC) {
    __shared__ __align__(16) char smem[24832];
    const int tid = threadIdx.x;

    if ((blockIdx.x & 1) == 0) {
        // ------------------- xw0 role -------------------
        const int xb = blockIdx.x >> 1;
        unsigned short* xsb = (unsigned short*)smem;      // [64][130] bf16
        float* w0s = (float*)(smem + 16640);              // [128*16]
        for (int i = tid; i < F_IN * F_HID; i += 256) w0s[i] = W0[i];
        const int row0 = xb * 64;
        for (int i = tid; i < 64 * 32; i += 256) {
            int r = i >> 5, c4 = i & 31;
            float4 v = make_float4(0.f, 0.f, 0.f, 0.f);
            int row = row0 + r;
            if (row < N_NODES) v = ((const float4*)(x + (size_t)row * F_IN))[c4];
            *(ushort2*)(xsb + r * 130 + c4 * 4)     = make_ushort2(f2bf_rne(v.x), f2bf_rne(v.y));
            *(ushort2*)(xsb + r * 130 + c4 * 4 + 2) = make_ushort2(f2bf_rne(v.z), f2bf_rne(v.w));
        }
        __syncthreads();
        const int r  = tid & 63;
        const int cg = tid >> 6;                          // 4 features per thread
        float a0 = 0.f, a1 = 0.f, a2 = 0.f, a3 = 0.f;
        #pragma unroll 4
        for (int k = 0; k < F_IN; k += 2) {
            unsigned u = *(const unsigned*)(xsb + r * 130 + k);
            float xv0 = __uint_as_float(u << 16);
            float xv1 = __uint_as_float(u & 0xFFFF0000u);
            const float* wr0 = w0s + k * F_HID + cg * 4;
            const float* wr1 = wr0 + F_HID;
            a0 = fmaf(xv0, wr0[0], a0); a1 = fmaf(xv0, wr0[1], a1);
            a2 = fmaf(xv0, wr0[2], a2); a3 = fmaf(xv0, wr0[3], a3);
            a0 = fmaf(xv1, wr1[0], a0); a1 = fmaf(xv1, wr1[1], a1);
            a2 = fmaf(xv1, wr1[2], a2); a3 = fmaf(xv1, wr1[3], a3);
        }
        int row = row0 + r;
        if (row < N_NODES) {
            ushort4 p = make_ushort4(f2bf_rne(a0), f2bf_rne(a1),
                                     f2bf_rne(a2), f2bf_rne(a3));
            *(ushort4*)(z0b + (size_t)row * F_HID + cg * 4) = p;
        }
    } else {
        // ------------------- bin role -------------------
        const int ch = blockIdx.x >> 1;
        int2* stage = (int2*)smem;                             // 16384 B
        unsigned char* sbid = (unsigned char*)(smem + 16384);  // 2048 B
        int* cnt  = (int*)(smem + 18432);                      // 256 ints
        int* excl = (int*)(smem + 19456);
        int* run  = (int*)(smem + 20480);
        int* gb   = (int*)(smem + 21504);
        int* alw  = (int*)(smem + 22528);
        int* wtot = (int*)(smem + 23552);                      // 4 ints
        const int e0  = ch * CH1;
        const int nch = min(CH1, N_EDGES - e0);

        cnt[tid] = 0;
        __syncthreads();

        int es[8], eb[8], edl[8]; float ww[8];
        #pragma unroll
        for (int k = 0; k < 8; ++k) {
            int idx = k * 256 + tid;
            if (idx < nch) {
                int e = e0 + idx;
                int d = dst[e];
                es[k]  = src[e];
                ww[k]  = ew[e];
                eb[k]  = d >> BK_LG;
                edl[k] = d & (BK_NODES - 1);
                atomicAdd(&cnt[eb[k]], 1);
            } else {
                eb[k] = -1;
            }
        }
        __syncthreads();

        // exclusive scan of cnt[0..256) via 4-wave shuffle
        {
            const int lane = tid & 63, wid = tid >> 6;
            int c_ = cnt[tid], inc = c_;
            #pragma unroll
            for (int off = 1; off < 64; off <<= 1) {
                int t = __shfl_up(inc, off);
                if (lane >= off) inc += t;
            }
            if (lane == 63) wtot[wid] = inc;
            __syncthreads();
            int base = 0;
            #pragma unroll
            for (int w = 0; w < 4; ++w) base += (w < wid) ? wtot[w] : 0;
            excl[tid] = base + inc - c_;
        }
        __syncthreads();

        if (tid < NBK) {
            int c = cnt[tid];
            if (c > 0) {
                int old = atomicAdd(&cursorC[tid * CUR_STRIDE], c);
                int a = BCAP - old;
                a = (a < 0) ? 0 : ((a > c) ? c : a);
                alw[tid] = a;
                gb[tid]  = tid * BCAP + old;
            } else {
                alw[tid] = 0;
                gb[tid]  = tid * BCAP;
            }
            run[tid] = 0;
        }
        __syncthreads();

        #pragma unroll
        for (int k = 0; k < 8; ++k) {
            if (eb[k] >= 0) {
                int b = eb[k];
                int p = excl[b] + atomicAdd(&run[b], 1);
                stage[p] = make_int2(__float_as_int(ww[k]), es[k] | (edl[k] << 17));
                sbid[p]  = (unsigned char)b;
            }
        }
        __syncthreads();

        for (int s = tid; s < nch; s += 256) {
            int b   = sbid[s];
            int off = s - excl[b];
            if (off < alw[b]) ebinC[(size_t)gb[b] + off] = stage[s];
        }
    }
}

// ---------------------------------------------------------------------------
// K2: per-bucket counting sort -> EXACT CSR in global (sortedC) + rowinfo.
// One block per bucket: hist (LDS) -> wave-shuffle scan -> direct place.
// Slab is dense-filled -> full-line L2 writeback; 2nd slab read is L2-hot.
// ---------------------------------------------------------------------------
__global__ __launch_bounds__(512) void k_sort2(const int* __restrict__ cursorC,
                                               const int2* __restrict__ ebinC,
                                               int2* __restrict__ sortedC,
                                               int2* __restrict__ rowinfo) {
    __shared__ int dcnt[BK_NODES], excl[BK_NODES], run[BK_NODES];
    __shared__ int wtot[8];
    const int tid = threadIdx.x, lane = tid & 63, wid = tid >> 6;
    const int c = blockIdx.x;
    dcnt[tid] = 0; run[tid] = 0;
    __syncthreads();
    const int   ecnt = min(cursorC[c * CUR_STRIDE], BCAP);
    const int2* eC   = ebinC + (size_t)c * BCAP;
    for (int i = tid; i < ecnt; i += 512) atomicAdd(&dcnt[eC[i].y >> 17], 1);
    __syncthreads();
    int d_ = dcnt[tid], inc = d_;
    #pragma unroll
    for (int off = 1; off < 64; off <<= 1) {
        int t = __shfl_up(inc, off);
        if (lane >= off) inc += t;
    }
    if (lane == 63) wtot[wid] = inc;
    __syncthreads();
    int base = 0;
    #pragma unroll
    for (int w = 0; w < 8; ++w) base += (w < wid) ? wtot[w] : 0;
    int ex = base + inc - d_;
    excl[tid] = ex;
    int v = c * BK_NODES + tid;
    if (v < N_NODES) rowinfo[v] = make_int2(c * BCAP + ex, d_);
    __syncthreads();
    int2* oB = sortedC + (size_t)c * BCAP;
    for (int i = tid; i < ecnt; i += 512) {
        int2 e = eC[i];                       // L2-hot re-read
        int dl = e.y >> 17;
        int p  = excl[dl] + atomicAdd(&run[dl], 1);
        oB[p] = e;
    }
}

// ---------------------------------------------------------------------------
// K3: gather layer 0 + fused relu/b0/W1-dot. One wave per node, tiny LDS.
// 8 feature-pair lanes (bf16x2) x 8-way edge parallel, unroll 2.
// ---------------------------------------------------------------------------
__global__ __launch_bounds__(256) void k_g0(const int2* __restrict__ rowinfo,
                                            const int2* __restrict__ sortedC,
                                            const unsigned short* __restrict__ z0b,
                                            const float* __restrict__ b0,
                                            const float* __restrict__ W1,
                                            float* __restrict__ z1) {
    __shared__ float b0s[16], w1s[16];
    const int tid = threadIdx.x;
    if (tid < 16) { b0s[tid] = b0[tid]; w1s[tid] = W1[tid]; }
    __syncthreads();
    const int lane = tid & 63;
    const int v    = blockIdx.x * 4 + (tid >> 6);
    if (v >= N_NODES) return;
    const int2 ri  = rowinfo[v];
    const int2* sl = sortedC + ri.x;
    const int dv   = ri.y;
    const int f2   = lane & 7;
    const int g    = lane >> 3;
    float acc0 = 0.f, acc1 = 0.f;
    for (int j = g; j < dv; j += 16) {
        int2 e0 = sl[j];
        int  j1 = j + 8;
        int2 e1 = (j1 < dv) ? sl[j1] : make_int2(0, 0);
        unsigned u0 = *(const unsigned*)(z0b + (size_t)(e0.y & 0x1FFFF) * F_HID + f2 * 2);
        unsigned u1 = *(const unsigned*)(z0b + (size_t)(e1.y & 0x1FFFF) * F_HID + f2 * 2);
        float w0 = __int_as_float(e0.x), w1 = __int_as_float(e1.x);
        acc0 = fmaf(__uint_as_float(u0 << 16),         w0, acc0);
        acc1 = fmaf(__uint_as_float(u0 & 0xFFFF0000u), w0, acc1);
        acc0 = fmaf(__uint_as_float(u1 << 16),         w1, acc0);
        acc1 = fmaf(__uint_as_float(u1 & 0xFFFF0000u), w1, acc1);
    }
    acc0 += __shfl_xor(acc0, 8);  acc1 += __shfl_xor(acc1, 8);
    acc0 += __shfl_xor(acc0, 16); acc1 += __shfl_xor(acc1, 16);
    acc0 += __shfl_xor(acc0, 32); acc1 += __shfl_xor(acc1, 32);
    float cc = fmaxf(acc0 + b0s[f2 * 2], 0.f) * w1s[f2 * 2]
             + fmaxf(acc1 + b0s[f2 * 2 + 1], 0.f) * w1s[f2 * 2 + 1];
    cc += __shfl_xor(cc, 1);
    cc += __shfl_xor(cc, 2);
    cc += __shfl_xor(cc, 4);
    if (lane == 0) z1[v] = cc;
}

// ---------------------------------------------------------------------------
// K4: gather layer 1 + sigmoid. 8 lanes per node from contiguous CSR.
// ---------------------------------------------------------------------------
__global__ __launch_bounds__(256) void k_g1(const int2* __restrict__ rowinfo,
                                            const int2* __restrict__ sortedC,
                                            const float* __restrict__ z1,
                                            const float* __restrict__ b1,
                                            float* __restrict__ out) {
    const int tid = threadIdx.x;
    const int l8  = tid & 7;
    const int v   = blockIdx.x * 32 + (tid >> 3);
    if (v >= N_NODES) return;
    const int2 ri  = rowinfo[v];
    const int2* sl = sortedC + ri.x;
    const int dv   = ri.y;
    float acc = 0.f;
    for (int j = l8; j < dv; j += 16) {
        int2 e0 = sl[j];
        int  j1 = j + 8;
        int2 e1 = (j1 < dv) ? sl[j1] : make_int2(0, 0);
        acc = fmaf(z1[e0.y & 0x1FFFF], __int_as_float(e0.x), acc);
        acc = fmaf(z1[e1.y & 0x1FFFF], __int_as_float(e1.x), acc);
    }
    #pragma unroll
    for (int off = 1; off < 8; off <<= 1) acc += __shfl_xor(acc, off);
    if (l8 == 0) {
        float t = acc + b1[0];
        out[v] = 1.f / (1.f + expf(-t));
    }
}

extern "C" void kernel_launch(void* const* d_in, const int* in_sizes, int n_in,
                              void* d_out, int out_size, void* d_ws, size_t ws_size,
                              hipStream_t stream) {
    const float* x   = (const float*)d_in[0];
    const int*   src = (const int*)d_in[1];
    const int*   dst = (const int*)d_in[2];
    const float* ew  = (const float*)d_in[3];
    const float* W0  = (const float*)d_in[4];
    const float* b0  = (const float*)d_in[5];
    const float* W1  = (const float*)d_in[6];
    const float* b1  = (const float*)d_in[7];
    float* out = (float*)d_out;

    // Workspace (~60 MB): z0b | z1 | cursorC | rowinfo | ebinC | sortedC
    unsigned short* z0b = (unsigned short*)d_ws;                 // 3.2 MB
    float* z1      = (float*)(z0b + (size_t)N_NODES * F_HID);    // 400 KB
    int*   cursorC = (int*)(z1 + N_NODES);                       // 12.5 KB
    int2*  rowinfo = (int2*)(cursorC + NBK * CUR_STRIDE);        // 800 KB
    int2*  ebinC   = rowinfo + N_NODES;                          // 27.7 MB
    int2*  sortedC = ebinC + (size_t)NBK * BCAP;                 // 27.7 MB

    hipMemsetAsync(cursorC, 0, (size_t)NBK * CUR_STRIDE * sizeof(int), stream);

    k_pre  <<<2 * NCH1, 256, 0, stream>>>(x, W0, z0b, src, dst, ew, cursorC, ebinC);
    k_sort2<<<NBK, 512, 0, stream>>>(cursorC, ebinC, sortedC, rowinfo);
    k_g0   <<<(N_NODES + 3) / 4,   256, 0, stream>>>(rowinfo, sortedC, z0b, b0, W1, z1);
    k_g1   <<<(N_NODES + 31) / 32, 256, 0, stream>>>(rowinfo, sortedC, z1, b1, out);
}

// Round 11
// 135.394 us; speedup vs baseline: 1.1186x; 1.1186x over previous
//
#include <hip/hip_runtime.h>

#define N_NODES 100000
#define N_EDGES 3200000
#define F_IN 128
#define F_HID 16

// fine buckets (consumer-facing)
#define BK_LG 7
#define BK_NODES 128
#define NB ((N_NODES + BK_NODES - 1) / BK_NODES)      // 782
#define BCAPF 4736                                    // avg 4093, +10 sigma
// coarse buckets (pass-1)
#define CLG 10
#define CNODES 1024
#define NBC ((N_NODES + CNODES - 1) / CNODES)         // 98
#define NBC_P 128
#define BCAPC 34816                                   // avg 32768, +11 sigma
#define CPB2 9                                        // pass-2 chunks per coarse
#define CHUNK2 4096
#define CHUNK1 2048                                   // pass-1 chunk (256 threads)
#define NCH1 ((N_EDGES + CHUNK1 - 1) / CHUNK1)        // 1563
#define NXB ((N_NODES + 63) / 64)                     // 1563 xw0 tiles
#define CUR_STRIDE 16

__device__ __forceinline__ unsigned short f2bf_rne(float f) {
    unsigned u = __float_as_uint(f);
    u += 0x7FFFu + ((u >> 16) & 1u);
    return (unsigned short)(u >> 16);
}

// ---------------------------------------------------------------------------
// K1 (fused producer, 24.8KB LDS union -> 6 blocks/CU):
//   even blocks: xw0 tile (64 rows, x staged as BF16) -> z0b
//   odd  blocks: pass-1 bin chunk into coarse 1024-node buckets
// ---------------------------------------------------------------------------
__global__ __launch_bounds__(256) void k_pre(const float* __restrict__ x,
                                             const float* __restrict__ W0,
                                             unsigned short* __restrict__ z0b,
                                             const int* __restrict__ src,
                                             const int* __restrict__ dst,
                                             const float* __restrict__ ew,
                                             int* __restrict__ cursorC,
                                             int2* __restrict__ ebinC) {
    __shared__ __align__(16) char smem[24832];
    const int tid = threadIdx.x;

    if ((blockIdx.x & 1) == 0) {
        // ------------------- xw0 role (bf16-staged x) -------------------
        const int xb = blockIdx.x >> 1;
        if (xb >= NXB) return;
        unsigned short* xsb = (unsigned short*)smem;      // [64][130] bf16
        float* w0s = (float*)(smem + 16640);              // [128*16] f32
        for (int i = tid; i < F_IN * F_HID; i += 256) w0s[i] = W0[i];
        const int row0 = xb * 64;
        for (int i = tid; i < 64 * 32; i += 256) {
            int r = i >> 5, c4 = i & 31;
            float4 v = make_float4(0.f, 0.f, 0.f, 0.f);
            int row = row0 + r;
            if (row < N_NODES) v = ((const float4*)(x + (size_t)row * F_IN))[c4];
            *(ushort2*)(xsb + r * 130 + c4 * 4)     = make_ushort2(f2bf_rne(v.x), f2bf_rne(v.y));
            *(ushort2*)(xsb + r * 130 + c4 * 4 + 2) = make_ushort2(f2bf_rne(v.z), f2bf_rne(v.w));
        }
        __syncthreads();
        const int r  = tid & 63;
        const int cg = tid >> 6;                          // 4 output cols/thread
        float a0 = 0.f, a1 = 0.f, a2 = 0.f, a3 = 0.f;
        #pragma unroll 4
        for (int k = 0; k < F_IN; k += 2) {
            unsigned u = *(const unsigned*)(xsb + r * 130 + k);
            float xv0 = __uint_as_float(u << 16);
            float xv1 = __uint_as_float(u & 0xFFFF0000u);
            const float* wr0 = w0s + k * F_HID + cg * 4;
            const float* wr1 = wr0 + F_HID;
            a0 = fmaf(xv0, wr0[0], a0); a1 = fmaf(xv0, wr0[1], a1);
            a2 = fmaf(xv0, wr0[2], a2); a3 = fmaf(xv0, wr0[3], a3);
            a0 = fmaf(xv1, wr1[0], a0); a1 = fmaf(xv1, wr1[1], a1);
            a2 = fmaf(xv1, wr1[2], a2); a3 = fmaf(xv1, wr1[3], a3);
        }
        int row = row0 + r;
        if (row < N_NODES) {
            ushort4 p = make_ushort4(f2bf_rne(a0), f2bf_rne(a1),
                                     f2bf_rne(a2), f2bf_rne(a3));
            *(ushort4*)(z0b + (size_t)row * F_HID + cg * 4) = p;
        }
    } else {
        // ------------------- bin1 role (coarse buckets) -------------------
        const int ch = blockIdx.x >> 1;
        if (ch >= NCH1) return;
        int2* stage = (int2*)smem;                            // 16384 B
        unsigned char* sbid = (unsigned char*)(smem + 16384); // 2048 B
        int* cnt  = (int*)(smem + 18432);                     // 128 ints (512B)
        int* excl = (int*)(smem + 18944);
        int* run  = (int*)(smem + 19456);
        int* gb   = (int*)(smem + 19968);
        int* alw  = (int*)(smem + 20480);
        int* wtot = (int*)(smem + 20992);
        const int e0  = ch * CHUNK1;
        const int nch = min(CHUNK1, N_EDGES - e0);

        for (int i = tid; i < NBC_P; i += 256) cnt[i] = 0;
        __syncthreads();

        const int EPT1 = CHUNK1 / 256;            // 8
        int es[8], eb[8], edl[8]; float ww[8];
        #pragma unroll
        for (int k = 0; k < EPT1; ++k) {
            int idx = k * 256 + tid;
            if (idx < nch) {
                int e = e0 + idx;
                int d = dst[e];
                es[k]  = src[e];
                ww[k]  = ew[e];
                eb[k]  = d >> CLG;
                edl[k] = d & (CNODES - 1);
                atomicAdd(&cnt[eb[k]], 1);
            } else {
                eb[k] = -1;
            }
        }
        __syncthreads();

        // exclusive scan of cnt[0..128) via 2-wave shuffle
        {
            const int lane = tid & 63;
            int inc = 0, dv_ = 0;
            if (tid < NBC_P) {
                dv_ = cnt[tid];
                inc = dv_;
                #pragma unroll
                for (int off = 1; off < 64; off <<= 1) {
                    int t = __shfl_up(inc, off);
                    if (lane >= off) inc += t;
                }
                if (lane == 63) wtot[tid >> 6] = inc;
            }
            __syncthreads();
            if (tid < NBC_P) {
                int base = (tid >= 64) ? wtot[0] : 0;
                excl[tid] = base + inc - dv_;
            }
        }
        __syncthreads();

        if (tid < NBC) {
            int c = cnt[tid];
            if (c > 0) {
                int old = atomicAdd(&cursorC[tid * CUR_STRIDE], c);
                int a = BCAPC - old;
                a = (a < 0) ? 0 : ((a > c) ? c : a);
                alw[tid] = a;
                gb[tid]  = tid * BCAPC + old;
            } else {
                alw[tid] = 0;
                gb[tid]  = tid * BCAPC;
            }
            run[tid] = 0;
        }
        __syncthreads();

        #pragma unroll
        for (int k = 0; k < EPT1; ++k) {
            if (eb[k] >= 0) {
                int b = eb[k];
                int p = excl[b] + atomicAdd(&run[b], 1);
                stage[p] = make_int2(__float_as_int(ww[k]), es[k] | (edl[k] << 17));
                sbid[p]  = (unsigned char)b;
            }
        }
        __syncthreads();

        for (int s = tid; s < nch; s += 256) {
            int b   = sbid[s];
            int off = s - excl[b];
            if (off < alw[b]) ebinC[(size_t)gb[b] + off] = stage[s];
        }
    }
}

// ---------------------------------------------------------------------------
// K2: pass-2 split coarse->fine (8-way) + per-node degree histogram.
// ---------------------------------------------------------------------------
__global__ __launch_bounds__(512) void k_bin2(const int* __restrict__ cursorC,
                                              const int2* __restrict__ ebinC,
                                              int* __restrict__ cursorF,
                                              int2* __restrict__ ebinF,
                                              int* __restrict__ deg) {
    __shared__ int cntw[64], runw[64], base[64];
    __shared__ int totals[8], excl_s[8], gb8[8], alw8[8];
    __shared__ int dcnt[CNODES];
    __shared__ int2 stage[CHUNK2];
    __shared__ unsigned char sbid[CHUNK2];
    const int tid = threadIdx.x;
    const int wid = tid >> 6;
    const int c   = blockIdx.x / CPB2;
    const int ck  = blockIdx.x % CPB2;
    const int ecnt = min(cursorC[c * CUR_STRIDE], BCAPC);
    const int beg  = ck * CHUNK2;
    const int n2   = min(CHUNK2, ecnt - beg);
    if (n2 <= 0) return;
    const int2* eC = ebinC + (size_t)c * BCAPC + beg;

    if (tid < 64) { cntw[tid] = 0; runw[tid] = 0; }
    for (int i = tid; i < CNODES; i += 512) dcnt[i] = 0;
    __syncthreads();

    const int EPT2 = CHUNK2 / 512;               // 8
    int fid[8]; int2 pk[8];
    #pragma unroll
    for (int k = 0; k < EPT2; ++k) {
        int idx = k * 512 + tid;
        if (idx < n2) {
            int2 e = eC[idx];
            int dlc = e.y >> 17;
            int f   = dlc >> BK_LG;
            fid[k]  = f;
            pk[k]   = make_int2(e.x, (e.y & 0x1FFFF) | ((dlc & (BK_NODES - 1)) << 17));
            atomicAdd(&cntw[f * 8 + wid], 1);
            atomicAdd(&dcnt[dlc], 1);
        } else {
            fid[k] = -1;
        }
    }
    __syncthreads();

    if (tid < 8) {
        int t = 0;
        #pragma unroll
        for (int w = 0; w < 8; ++w) t += cntw[tid * 8 + w];
        totals[tid] = t;
    }
    __syncthreads();
    if (tid < 8) {
        int e = 0;
        for (int f = 0; f < 8; ++f) if (f < tid) e += totals[f];
        excl_s[tid] = e;
        int t = totals[tid];
        int fb = c * 8 + tid;
        if (t > 0 && fb < NB) {
            int old = atomicAdd(&cursorF[fb * CUR_STRIDE], t);
            int a = BCAPF - old;
            a = (a < 0) ? 0 : ((a > t) ? t : a);
            alw8[tid] = a;
            gb8[tid]  = fb * BCAPF + old;
        } else {
            alw8[tid] = 0;
            gb8[tid]  = 0;
        }
    }
    __syncthreads();
    if (tid < 64) {
        int f = tid >> 3, w = tid & 7;
        int bb = excl_s[f];
        for (int w2 = 0; w2 < 8; ++w2) if (w2 < w) bb += cntw[f * 8 + w2];
        base[tid] = bb;
    }
    __syncthreads();

    #pragma unroll
    for (int k = 0; k < EPT2; ++k) {
        if (fid[k] >= 0) {
            int slot = fid[k] * 8 + wid;
            int p = base[slot] + atomicAdd(&runw[slot], 1);
            stage[p] = pk[k];
            sbid[p]  = (unsigned char)fid[k];
        }
    }
    __syncthreads();

    for (int s = tid; s < n2; s += 512) {
        int f   = sbid[s];
        int off = s - excl_s[f];
        if (off < alw8[f]) ebinF[(size_t)gb8[f] + off] = stage[s];
    }

    // flush per-node degree counts (striped, ~1K atomics/block)
    for (int i = tid; i < CNODES; i += 512) {
        int d = dcnt[i];
        int v = c * CNODES + i;
        if (d > 0 && v < N_NODES) atomicAdd(&deg[v], d);
    }
}

// ---------------------------------------------------------------------------
// K3: gather layer 0 with direct-place LDS sort (deg precomputed).
// ---------------------------------------------------------------------------
__global__ __launch_bounds__(512) void k_sg0(const int* __restrict__ deg,
                                             const int2* __restrict__ ebinF,
                                             const unsigned short* __restrict__ z0b,
                                             const float* __restrict__ b0,
                                             const float* __restrict__ W1,
                                             float* __restrict__ z1) {
    __shared__ int2 sorted[BCAPF];               // 37.9 KB
    __shared__ int scn[BK_NODES], dg[BK_NODES], run[BK_NODES];
    __shared__ int wtot[2], ecnt_s;
    __shared__ float b0s[16], w1s[16];
    const int tid  = threadIdx.x;
    const int lane = tid & 63, wid = tid >> 6;
    const int b    = blockIdx.x;
    if (tid < 16) { b0s[tid] = b0[tid]; w1s[tid] = W1[tid]; }

    int inc = 0, d_ = 0;
    if (tid < BK_NODES) {
        int v = b * BK_NODES + tid;
        d_ = (v < N_NODES) ? deg[v] : 0;
        dg[tid]  = d_;
        run[tid] = 0;
        inc = d_;
        #pragma unroll
        for (int off = 1; off < 64; off <<= 1) {
            int t = __shfl_up(inc, off);
            if (lane >= off) inc += t;
        }
        if (lane == 63) wtot[tid >> 6] = inc;
    }
    __syncthreads();
    if (tid < BK_NODES) {
        int base = (tid >= 64) ? wtot[0] : 0;
        scn[tid] = base + inc - d_;
        if (tid == BK_NODES - 1) ecnt_s = min(base + inc, BCAPF);
    }
    __syncthreads();

    const int ecnt = ecnt_s;
    const int2* eb = ebinF + (size_t)b * BCAPF;
    for (int i = tid; i < ecnt; i += 512) {
        int2 e  = eb[i];
        int  dl = e.y >> 17;
        int  p  = scn[dl] + atomicAdd(&run[dl], 1);
        if (p < BCAPF) sorted[p] = e;
    }
    __syncthreads();

    for (int n = wid; n < BK_NODES; n += 8) {
        const int v = b * BK_NODES + n;
        if (v >= N_NODES) continue;
        const int beg = scn[n];
        const int end = min(beg + dg[n], BCAPF);
        const int dv  = end - beg;
        const int f2  = lane & 7;
        const int g   = lane >> 3;
        float acc0 = 0.f, acc1 = 0.f;
        for (int j = g; j < dv; j += 16) {
            int2 e0 = sorted[beg + j];
            int  j1 = j + 8;
            int2 e1 = (j1 < dv) ? sorted[beg + j1] : make_int2(0, 0);
            unsigned u0 = *(const unsigned*)(z0b + (size_t)(e0.y & 0x1FFFF) * F_HID + f2 * 2);
            unsigned u1 = *(const unsigned*)(z0b + (size_t)(e1.y & 0x1FFFF) * F_HID + f2 * 2);
            float w0 = __int_as_float(e0.x), w1 = __int_as_float(e1.x);
            acc0 = fmaf(__uint_as_float(u0 << 16),         w0, acc0);
            acc1 = fmaf(__uint_as_float(u0 & 0xFFFF0000u), w0, acc1);
            acc0 = fmaf(__uint_as_float(u1 << 16),         w1, acc0);
            acc1 = fmaf(__uint_as_float(u1 & 0xFFFF0000u), w1, acc1);
        }
        acc0 += __shfl_xor(acc0, 8);  acc1 += __shfl_xor(acc1, 8);
        acc0 += __shfl_xor(acc0, 16); acc1 += __shfl_xor(acc1, 16);
        acc0 += __shfl_xor(acc0, 32); acc1 += __shfl_xor(acc1, 32);
        float cc = fmaxf(acc0 + b0s[f2 * 2], 0.f) * w1s[f2 * 2]
                 + fmaxf(acc1 + b0s[f2 * 2 + 1], 0.f) * w1s[f2 * 2 + 1];
        cc += __shfl_xor(cc, 1);
        cc += __shfl_xor(cc, 2);
        cc += __shfl_xor(cc, 4);
        if (lane == 0) z1[v] = cc;
    }
}

// ---------------------------------------------------------------------------
// K4: layer 1 from bucket-grouped ebinF: 1 LDS atomic/edge + fused sigmoid.
// ---------------------------------------------------------------------------
__global__ __launch_bounds__(256) void k_g1(const int* __restrict__ cursorF,
                                            const int2* __restrict__ ebinF,
                                            const float* __restrict__ z1,
                                            const float* __restrict__ b1,
                                            float* __restrict__ out) {
    __shared__ float acc[BK_NODES];
    const int tid = threadIdx.x;
    const int b   = blockIdx.x;
    if (tid < BK_NODES) acc[tid] = 0.f;
    __syncthreads();
    const int   ecnt = min(cursorF[b * CUR_STRIDE], BCAPF);
    const int2* eb   = ebinF + (size_t)b * BCAPF;
    for (int i = tid; i < ecnt; i += 512) {
        int2 e0 = eb[i];
        int  i1 = i + 256;
        int2 e1 = (i1 < ecnt) ? eb[i1] : make_int2(0, 0);
        float m0 = z1[e0.y & 0x1FFFF] * __int_as_float(e0.x);
        float m1 = z1[e1.y & 0x1FFFF] * __int_as_float(e1.x);
        atomicAdd(&acc[e0.y >> 17], m0);
        if (i1 < ecnt) atomicAdd(&acc[e1.y >> 17], m1);
    }
    __syncthreads();
    if (tid < BK_NODES) {
        int v = b * BK_NODES + tid;
        if (v < N_NODES) out[v] = 1.f / (1.f + expf(-(acc[tid] + b1[0])));
    }
}

extern "C" void kernel_launch(void* const* d_in, const int* in_sizes, int n_in,
                              void* d_out, int out_size, void* d_ws, size_t ws_size,
                              hipStream_t stream) {
    const float* x   = (const float*)d_in[0];
    const int*   src = (const int*)d_in[1];
    const int*   dst = (const int*)d_in[2];
    const float* ew  = (const float*)d_in[3];
    const float* W0  = (const float*)d_in[4];
    const float* b0  = (const float*)d_in[5];
    const float* W1  = (const float*)d_in[6];
    const float* b1  = (const float*)d_in[7];
    float* out = (float*)d_out;

    // Workspace (~61 MB): z0b | z1 | deg | cursorC | cursorF | ebinC | ebinF
    unsigned short* z0b = (unsigned short*)d_ws;                 // 3.2 MB
    float* z1      = (float*)(z0b + (size_t)N_NODES * F_HID);    // 400 KB
    int*   deg     = (int*)(z1 + N_NODES);                       // 400 KB
    int*   cursorC = deg + N_NODES;                              // 6.3 KB
    int*   cursorF = cursorC + NBC * CUR_STRIDE;                 // 50 KB
    int2*  ebinC   = (int2*)(cursorF + NB * CUR_STRIDE);         // 27.3 MB
    int2*  ebinF   = ebinC + (size_t)NBC * BCAPC;                // 29.6 MB

    hipMemsetAsync(deg, 0,
                   ((size_t)N_NODES + (size_t)(NBC + NB) * CUR_STRIDE) * sizeof(int),
                   stream);

    k_pre <<<2 * NCH1, 256, 0, stream>>>(x, W0, z0b, src, dst, ew, cursorC, ebinC);
    k_bin2<<<NBC * CPB2, 512, 0, stream>>>(cursorC, ebinC, cursorF, ebinF, deg);
    k_sg0 <<<NB, 512, 0, stream>>>(deg, ebinF, z0b, b0, W1, z1);
    k_g1  <<<NB, 256, 0, stream>>>(cursorF, ebinF, z1, b1, out);
}